// Round 2
// baseline (91.145 us; speedup 1.0000x reference)
//
#include <hip/hip_runtime.h>
#include <math.h>

#define RES 32
#define GRID_G (RES * RES * RES)   // 32768
#define NPTS 256
#define GPT 4                      // gaussians per thread (float4 width)
#define BLK 256
#define NB 16                      // n-chunk per block

__global__ __launch_bounds__(BLK) void gauss_splat_kernel(
    const float* __restrict__ points,     // [N,3]
    const float* __restrict__ positions,  // [G,3]
    const float* __restrict__ scales,     // [G,3]
    const float* __restrict__ rotations,  // [G,4]
    const float* __restrict__ opacity,    // [G]
    const float* __restrict__ sh,         // [G,9]
    float* __restrict__ out_rgb,          // [N,G]
    float* __restrict__ out_sigma)        // [G]
{
    const int g0 = (blockIdx.x * BLK + threadIdx.x) * GPT;  // 4 consecutive g
    const int n0 = blockIdx.y * NB;

    __shared__ float s_pts[NB][3];
    if (threadIdx.x < NB * 3)
        s_pts[threadIdx.x / 3][threadIdx.x % 3] = points[n0 * 3 + threadIdx.x] * 0.25f;
    __syncthreads();

    // ---- per-g state for GPT consecutive gaussians, all float4 loads ----
    float pos[GPT * 3];
    {
        const float4* p = reinterpret_cast<const float4*>(positions + (size_t)g0 * 3);
        float4 a = p[0], b = p[1], c = p[2];
        pos[0]=a.x; pos[1]=a.y; pos[2]=a.z; pos[3]=a.w;
        pos[4]=b.x; pos[5]=b.y; pos[6]=b.z; pos[7]=b.w;
        pos[8]=c.x; pos[9]=c.y; pos[10]=c.z; pos[11]=c.w;
    }
    float isc[GPT * 3];
    {
        const float4* p = reinterpret_cast<const float4*>(scales + (size_t)g0 * 3);
        float4 a = p[0], b = p[1], c = p[2];
        float t[12] = {a.x,a.y,a.z,a.w, b.x,b.y,b.z,b.w, c.x,c.y,c.z,c.w};
        #pragma unroll
        for (int i = 0; i < 12; ++i) isc[i] = 1.0f / (t[i] + 1e-6f);
    }
    float M[GPT][9];
    {
        const float4* p = reinterpret_cast<const float4*>(rotations + (size_t)g0 * 4);
        #pragma unroll
        for (int i = 0; i < GPT; ++i) {
            float4 q = p[i];
            const float q0 = q.x, q1 = q.y, q2 = q.z, q3 = q.w;
            M[i][0] = 1.f - 2.f * (q2*q2 + q3*q3);
            M[i][1] = 2.f * (q1*q2 - q0*q3);
            M[i][2] = 2.f * (q1*q3 + q0*q2);
            M[i][3] = 2.f * (q1*q2 + q0*q3);
            M[i][4] = 1.f - 2.f * (q1*q1 + q3*q3);
            M[i][5] = 2.f * (q2*q3 - q0*q1);
            M[i][6] = 2.f * (q1*q3 - q0*q2);
            M[i][7] = 2.f * (q2*q3 + q0*q1);
            M[i][8] = 1.f - 2.f * (q1*q1 + q2*q2);
        }
    }
    float S[GPT][9];
    {
        const float c0  = 0.28209479177387814f;
        const float c1  = 0.48860251190291992f;
        const float c2a = 0.54627421529603959f;
        const float c2b = 0.15769578262626002f;
        const float c2c = 0.27313710764801980f;
        const float kk[9] = {c0, c1, c1, c1, c2a, c2a, c2b, c2a, c2c};
        const float4* p = reinterpret_cast<const float4*>(sh + (size_t)g0 * 9);
        float t[GPT * 9];
        #pragma unroll
        for (int i = 0; i < 9; ++i) {
            float4 v = p[i];
            t[i*4+0] = v.x; t[i*4+1] = v.y; t[i*4+2] = v.z; t[i*4+3] = v.w;
        }
        #pragma unroll
        for (int i = 0; i < GPT; ++i)
            #pragma unroll
            for (int j = 0; j < 9; ++j) S[i][j] = t[i*9 + j] * kk[j];
    }

    // sigma = softplus(opacity), vectorized, written once
    if (blockIdx.y == 0) {
        float4 o = *reinterpret_cast<const float4*>(opacity + g0);
        float ov[4] = {o.x, o.y, o.z, o.w};
        float sv[4];
        #pragma unroll
        for (int i = 0; i < 4; ++i)
            sv[i] = fmaxf(ov[i], 0.f) + log1pf(expf(-fabsf(ov[i])));
        *reinterpret_cast<float4*>(out_sigma + g0) = make_float4(sv[0], sv[1], sv[2], sv[3]);
    }

    // ---- n loop: 4 rgb values per iter, one float4 store ----
    #pragma unroll 2
    for (int k = 0; k < NB; ++k) {
        const float ptx = s_pts[k][0], pty = s_pts[k][1], ptz = s_pts[k][2];
        float rgb[GPT];
        #pragma unroll
        for (int i = 0; i < GPT; ++i) {
            const float dsx = (ptx - pos[i*3+0]) * isc[i*3+0];
            const float dsy = (pty - pos[i*3+1]) * isc[i*3+1];
            const float dsz = (ptz - pos[i*3+2]) * isc[i*3+2];

            const float rx = fmaf(M[i][0], dsx, fmaf(M[i][1], dsy, M[i][2] * dsz));
            const float ry = fmaf(M[i][3], dsx, fmaf(M[i][4], dsy, M[i][5] * dsz));
            const float rz = fmaf(M[i][6], dsx, fmaf(M[i][7], dsy, M[i][8] * dsz));

            const float inv = rsqrtf(fmaf(rx, rx, fmaf(ry, ry, rz * rz)));
            const float x = rx * inv, y = ry * inv, z = rz * inv;

            float d = S[i][0];
            d = fmaf(S[i][1], y, d);
            d = fmaf(S[i][2], z, d);
            d = fmaf(S[i][3], x, d);
            d = fmaf(S[i][4], x * y, d);
            d = fmaf(S[i][5], y * z, d);
            d = fmaf(S[i][6], fmaf(3.f, z * z, -1.f), d);
            d = fmaf(S[i][7], x * z, d);
            d = fmaf(S[i][8], fmaf(x, x, -(y * y)), d);

            rgb[i] = 1.f / (1.f + expf(-d));
        }
        *reinterpret_cast<float4*>(out_rgb + (size_t)(n0 + k) * GRID_G + g0) =
            make_float4(rgb[0], rgb[1], rgb[2], rgb[3]);
    }
}

extern "C" void kernel_launch(void* const* d_in, const int* in_sizes, int n_in,
                              void* d_out, int out_size, void* d_ws, size_t ws_size,
                              hipStream_t stream) {
    const float* points    = (const float*)d_in[0];
    const float* positions = (const float*)d_in[1];
    const float* scales    = (const float*)d_in[2];
    const float* rotations = (const float*)d_in[3];
    const float* opacity   = (const float*)d_in[4];
    const float* sh_coeff  = (const float*)d_in[5];

    float* out_rgb   = (float*)d_out;
    float* out_sigma = (float*)d_out + (size_t)NPTS * GRID_G;

    dim3 grid(GRID_G / (BLK * GPT), NPTS / NB);  // (32, 16) = 512 blocks
    dim3 block(BLK);
    gauss_splat_kernel<<<grid, block, 0, stream>>>(
        points, positions, scales, rotations, opacity, sh_coeff,
        out_rgb, out_sigma);
}